// Round 13
// baseline (291.583 us; speedup 1.0000x reference)
//
#include <hip/hip_runtime.h>
#include <hip/hip_fp16.h>

#define TILE 64
#define QCH 32          // CSR entries per staged Q chunk (32 x 512B = 16KB)
#define INCCAP 1024     // staged inc capacity (block range + alignment slack)

#define GLOAD_LDS(gptr, lptr, sz)                                              \
    __builtin_amdgcn_global_load_lds(                                          \
        (const __attribute__((address_space(1))) unsigned int*)(gptr),         \
        (__attribute__((address_space(3))) unsigned int*)(lptr), (sz), 0, 0)

// ---------------------------------------------------------------------------
// K1: HTh[n*B + b] = fp16( pred_p[b*N+n]*p_scale[n] + p_mean[n] + elev[n] )
// ---------------------------------------------------------------------------
__global__ void k_build_ht(const float* __restrict__ pred_p,
                           const float* __restrict__ p_scale,
                           const float* __restrict__ p_mean,
                           const float* __restrict__ elev,
                           __half* __restrict__ HTh,
                           int B, int N) {
    __shared__ __align__(16) float tile[TILE][TILE + 2];
    const int n0 = blockIdx.x * TILE;
    const int b0 = blockIdx.y * TILE;
    const int tn = threadIdx.x % TILE;
    const int tw = threadIdx.x / TILE;

    const int n = n0 + tn;
    float sc = 0.f, mn = 0.f, el = 0.f;
    if (n < N) { sc = p_scale[n]; mn = p_mean[n]; el = elev[n]; }

    #pragma unroll
    for (int i = 0; i < TILE / 4; ++i) {
        const int bl = i * 4 + tw;
        float v = 0.f;
        if (n < N) v = pred_p[(size_t)(b0 + bl) * N + n] * sc + mn + el;
        tile[tn][bl] = v;
    }
    __syncthreads();

    const int c  = threadIdx.x & 31;
    const int rg = threadIdx.x >> 5;
    #pragma unroll
    for (int i = 0; i < 8; ++i) {
        const int nl = i * 8 + rg;
        const int nn = n0 + nl;
        if (nn < N) {
            const float2 f = *reinterpret_cast<const float2*>(&tile[nl][2 * c]);
            __half2* dst = reinterpret_cast<__half2*>(HTh + (size_t)nn * B + b0);
            dst[c] = __floats2half2_rn(f.x, f.y);
        }
    }
}

// ---------------------------------------------------------------------------
// CSR build: hist -> scans -> fill.  inc[slot] = (edge<<1) | is_dst.
// ---------------------------------------------------------------------------
__global__ void k_hist(const int* __restrict__ nodes, int* __restrict__ deg, int M) {
    const int i = blockIdx.x * 256 + threadIdx.x;
    if (i < M) atomicAdd(&deg[nodes[i]], 1);
}

__global__ void k_scan1(const int* __restrict__ deg, int* __restrict__ bsum, int N) {
    __shared__ int s[256];
    const int i = blockIdx.x * 256 + threadIdx.x;
    s[threadIdx.x] = (i < N) ? deg[i] : 0;
    __syncthreads();
    #pragma unroll
    for (int off = 128; off >= 1; off >>= 1) {
        if (threadIdx.x < off) s[threadIdx.x] += s[threadIdx.x + off];
        __syncthreads();
    }
    if (threadIdx.x == 0) bsum[blockIdx.x] = s[0];
}

__global__ void k_scan2(int* __restrict__ bsum, int nb) {   // 1 block
    __shared__ int s[256];
    const int t = threadIdx.x;
    const int v = (t < nb) ? bsum[t] : 0;
    s[t] = v;
    __syncthreads();
    #pragma unroll
    for (int off = 1; off < 256; off <<= 1) {
        const int tmp = (t >= off) ? s[t - off] : 0;
        __syncthreads();
        s[t] += tmp;
        __syncthreads();
    }
    if (t < nb) bsum[t] = s[t] - v;
}

__global__ void k_scan3(const int* __restrict__ deg, const int* __restrict__ bsum,
                        int* __restrict__ offsets, int* __restrict__ cursor, int N) {
    __shared__ int s[256];
    const int t = threadIdx.x;
    const int i = blockIdx.x * 256 + t;
    const int v = (i < N) ? deg[i] : 0;
    s[t] = v;
    __syncthreads();
    #pragma unroll
    for (int off = 1; off < 256; off <<= 1) {
        const int tmp = (t >= off) ? s[t - off] : 0;
        __syncthreads();
        s[t] += tmp;
        __syncthreads();
    }
    const int excl = s[t] - v + bsum[blockIdx.x];
    if (i < N) { offsets[i] = excl; cursor[i] = excl; }
    if (i == N - 1) offsets[N] = excl + v;
}

__global__ void k_fill(const int* __restrict__ esrc, const int* __restrict__ edst,
                       int* __restrict__ cursor, int* __restrict__ inc, int E) {
    const int e = blockIdx.x * 256 + threadIdx.x;
    if (e < E) {
        const int ps = atomicAdd(&cursor[esrc[e]], 1);
        inc[ps] = (e << 1);            // outflow: -Q
        const int pd = atomicAdd(&cursor[edst[e]], 1);
        inc[pd] = (e << 1) | 1;        // inflow: +Q
    }
}

// ---------------------------------------------------------------------------
// K2: per (edge-tile, batch-slab): Q from pred_f -> LINEAR fp16 store into
// QT[E][256] (no atomics); head loss via hoisted fp16 HT gathers.
// ---------------------------------------------------------------------------
__global__ void k_edges(const float* __restrict__ pred_f,
                        const float* __restrict__ f_scale,
                        const float* __restrict__ f_mean,
                        const float* __restrict__ Rcoef,
                        const int* __restrict__ esrc,
                        const int* __restrict__ edst,
                        const __half* __restrict__ HTh,   // [N][B] fp16
                        __half* __restrict__ QT,          // [E][B] fp16
                        double* __restrict__ head_accum,
                        int B, int E) {
    __shared__ __align__(16) float qt[TILE][TILE + 2];
    __shared__ double wsum[4];
    const int e0 = blockIdx.x * TILE;
    const int b0 = blockIdx.y * TILE;
    const int te = threadIdx.x % TILE;
    const int tw = threadIdx.x / TILE;

    const int e = e0 + te;
    const float fs = f_scale[e];
    const float fm = f_mean[e];
    #pragma unroll
    for (int i = 0; i < TILE / 4; ++i) {
        const int bl = i * 4 + tw;
        qt[te][bl] = pred_f[(size_t)(b0 + bl) * E + e] * fs + fm;
    }
    __syncthreads();

    const int bl = te;
    const __half* HTb = HTh + b0 + bl;

    // hoisted gathers
    int   sarr[16], darr[16];
    float hs[16], hd[16];
    #pragma unroll
    for (int j = 0; j < 16; ++j) {
        const int ee = e0 + tw * 16 + j;
        sarr[j] = esrc[ee];
        darr[j] = edst[ee];
        hs[j] = __half2float(HTb[(size_t)sarr[j] * B]);
        hd[j] = __half2float(HTb[(size_t)darr[j] * B]);
    }

    // linear QT store: 2 edges per instruction, all 64 lanes active
    const int sel = bl >> 5;
    const int pc  = bl & 31;
    #pragma unroll
    for (int k = 0; k < 8; ++k) {
        const int el = tw * 16 + 2 * k + sel;
        const float2 q01 = *reinterpret_cast<const float2*>(&qt[el][2 * pc]);
        const __half2 h = __floats2half2_rn(q01.x, q01.y);
        *reinterpret_cast<__half2*>(
            (char*)QT + (size_t)(e0 + el) * B * 2 + (size_t)b0 * 2 + pc * 4) = h;
    }

    // head loss
    double head = 0.0;
    #pragma unroll
    for (int j = 0; j < 16; ++j) {
        const int el = tw * 16 + j;
        const int ee = e0 + el;
        const float q = qt[el][bl];
        const float aq = fabsf(q);
        const float pw = exp2f(0.852f * __log2f(aq));   // |q|^0.852
        const float fr = Rcoef[ee] * q * pw;
        const float t = (hs[j] - hd[j]) - fr;
        head += (double)t * (double)t;
    }

    #pragma unroll
    for (int off = 32; off >= 1; off >>= 1)
        head += __shfl_down(head, off, 64);
    if ((threadIdx.x & 63) == 0) wsum[threadIdx.x >> 6] = head;
    __syncthreads();
    if (threadIdx.x == 0)
        atomicAdd(head_accum, wsum[0] + wsum[1] + wsum[2] + wsum[3]);
}

// ---------------------------------------------------------------------------
// K3: CSR walk, NO atomics.  Block = 64 nodes; wave w owns nodes 16w..16w+15
// (contiguous CSR entry range).  Q rows DMA-staged (double-buffered); consume
// = ds_read_b64 + register adds; one 512B store per node.
// ---------------------------------------------------------------------------
__global__ __launch_bounds__(256) void k_node(
        const __half* __restrict__ QT,      // [E][256]
        const int* __restrict__ offsets,    // [N+1]
        const int* __restrict__ inc,        // [2E]
        __half* __restrict__ qaccG,         // [N][256] fp16
        int N, int E) {
    __shared__ __align__(16) char ldsQ[2][QCH * 512];   // 32KB
    __shared__ __align__(16) int ldsInc[INCCAP];        // 4KB
    __shared__ int ldsOffs[65];

    const int n0 = blockIdx.x * 64;
    const int tid = threadIdx.x;
    const int lane = tid & 63;
    const int w = tid >> 6;

    if (tid <= 64) {
        int idx = n0 + tid; if (idx > N) idx = N;
        ldsOffs[tid] = offsets[idx];
    }
    __syncthreads();
    const int beg = ldsOffs[0];
    const int end = ldsOffs[64];
    const int sbase  = beg & ~255;
    const int cbase0 = beg & ~(QCH - 1);
    const int nc = (end > cbase0) ? (end - cbase0 + QCH - 1) / QCH : 0;

    // stage all inc for the block range (<=4 DMAs x 1KB)
    {
        const int nsup = (end > sbase) ? (end - sbase + 255) / 256 : 0;
        for (int s = w; s < nsup; s += 4) {
            long gi = (long)(sbase + s * 256) + (long)lane * 4;
            const long gmax = (long)2 * E - 4;
            if (gi > gmax) gi = gmax;
            GLOAD_LDS(inc + gi, (char*)ldsInc + s * 1024, 16);
        }
    }
    __syncthreads();   // inc staged (barrier drains vmcnt)

    // per-wave walk state
    int cur = 16 * w;
    int kcur = ldsOffs[cur];
    int nb = ldsOffs[cur + 1];
    const int kend_w = ldsOffs[16 * w + 16];
    float qn0 = 0.f, qn1 = 0.f, qn2 = 0.f, qn3 = 0.f;

    // stage Q rows for chunk c
    auto stageQ = [&](int c) {
        const int cb = cbase0 + c * QCH;
        char* dstbase = ldsQ[c & 1];
        const int sel_ = lane >> 5;
        #pragma unroll
        for (int u = 0; u < 4; ++u) {
            const int i = w * 4 + u;
            int kk = cb + 2 * i + sel_;
            if (kk >= end) kk = end - 1;
            const int ev = ldsInc[kk - sbase] >> 1;
            const char* src = (const char*)QT + (size_t)ev * 512
                              + (size_t)(lane & 31) * 16;
            GLOAD_LDS(src, dstbase + i * 1024, 16);
        }
    };

    auto flush = [&](int c_) {
        const int n = n0 + c_;
        if (n < N) {
            const __half2 h0 = __floats2half2_rn(qn0, qn1);
            const __half2 h1 = __floats2half2_rn(qn2, qn3);
            uint2 u;
            u.x = *reinterpret_cast<const unsigned int*>(&h0);
            u.y = *reinterpret_cast<const unsigned int*>(&h1);
            *reinterpret_cast<uint2*>(
                (char*)qaccG + (size_t)n * 512 + (size_t)lane * 8) = u;
        }
        qn0 = qn1 = qn2 = qn3 = 0.f;
    };

    if (nc > 0) stageQ(0);
    __syncthreads();   // chunk 0 resident

    for (int c = 0; c < nc; ++c) {
        if (c + 1 < nc) stageQ(c + 1);
        const int cb = cbase0 + c * QCH;
        const int chi = (cb + QCH < end) ? cb + QCH : end;
        const char* buf = ldsQ[c & 1];

        int k = (kcur > cb) ? kcur : cb;
        while (k < chi && k < kend_w) {
            while (k >= nb && cur < 16 * w + 16) {
                flush(cur); ++cur; nb = ldsOffs[cur + 1];
            }
            const int iv = ldsInc[k - sbase];
            const uint2 v = *reinterpret_cast<const uint2*>(
                buf + (size_t)(k - cb) * 512 + (size_t)lane * 8);
            const __half2 a = *reinterpret_cast<const __half2*>(&v.x);
            const __half2 b2 = *reinterpret_cast<const __half2*>(&v.y);
            const float2 fa = __half22float2(a);
            const float2 fb = __half22float2(b2);
            if (iv & 1) { qn0 += fa.x; qn1 += fa.y; qn2 += fb.x; qn3 += fb.y; }
            else        { qn0 -= fa.x; qn1 -= fa.y; qn2 -= fb.x; qn3 -= fb.y; }
            ++k;
        }
        kcur = k;
        __syncthreads();   // next chunk resident; buffers swap
    }

    // epilogue: flush current partial + remaining (possibly empty) nodes
    while (cur < 16 * w + 16) { flush(cur); ++cur; }
}

// ---------------------------------------------------------------------------
// K4: loss_mass from qaccG (fp16 pairs) vs transposed true_d.
// ---------------------------------------------------------------------------
__global__ void k_mass(const float* __restrict__ true_d,
                       const float* __restrict__ d_scale,
                       const float* __restrict__ d_mean,
                       const __half2* __restrict__ acc2,  // [N][B/2]
                       double* __restrict__ mass_accum,
                       int B, int N) {
    __shared__ __align__(16) float dt[TILE][TILE + 2];
    __shared__ double wsum[4];
    const int n0 = blockIdx.x * TILE;
    const int b0 = blockIdx.y * TILE;
    const int tn = threadIdx.x % TILE;
    const int tw = threadIdx.x / TILE;
    const int halfB = B >> 1;

    const int n = n0 + tn;
    float sc = 0.f, mn = 0.f;
    if (n < N) { sc = d_scale[n]; mn = d_mean[n]; }
    #pragma unroll
    for (int i = 0; i < TILE / 4; ++i) {
        const int bl = i * 4 + tw;
        float v = 0.f;
        if (n < N) v = true_d[(size_t)(b0 + bl) * N + n] * sc + mn;
        dt[tn][bl] = v;
    }
    __syncthreads();

    double m = 0.0;
    const int tn2 = threadIdx.x & 31;
    const int tg  = threadIdx.x >> 5;
    const int pair0 = b0 >> 1;
    #pragma unroll
    for (int j = 0; j < 8; ++j) {
        const int nl = j * 8 + tg;
        const int nn = n0 + nl;
        if (nn < N) {
            const __half2 h = acc2[(size_t)nn * halfB + pair0 + tn2];
            const float2 f = __half22float2(h);
            const float2 dv = *reinterpret_cast<const float2*>(&dt[nl][2 * tn2]);
            const float t0 = f.x - dv.x;
            const float t1 = f.y - dv.y;
            m += (double)t0 * (double)t0 + (double)t1 * (double)t1;
        }
    }
    #pragma unroll
    for (int off = 32; off >= 1; off >>= 1)
        m += __shfl_down(m, off, 64);
    if ((threadIdx.x & 63) == 0) wsum[threadIdx.x >> 6] = m;
    __syncthreads();
    if (threadIdx.x == 0)
        atomicAdd(mass_accum, wsum[0] + wsum[1] + wsum[2] + wsum[3]);
}

// ---------------------------------------------------------------------------
__global__ void k_final(const double* __restrict__ accum,
                        float* __restrict__ out,
                        double inv_mass_count, double inv_head_count) {
    out[0] = (float)(accum[0] * inv_mass_count);
    out[1] = (float)(accum[1] * inv_head_count);
}

static inline size_t align256s(size_t x) { return (x + 255) & ~(size_t)255; }

extern "C" void kernel_launch(void* const* d_in, const int* in_sizes, int n_in,
                              void* d_out, int out_size, void* d_ws, size_t ws_size,
                              hipStream_t stream) {
    const float* pred_p  = (const float*)d_in[0];
    const float* pred_f  = (const float*)d_in[1];
    const float* true_d  = (const float*)d_in[2];
    const float* p_mean  = (const float*)d_in[3];
    const float* p_scale = (const float*)d_in[4];
    const float* f_mean  = (const float*)d_in[5];
    const float* f_scale = (const float*)d_in[6];
    const float* d_mean  = (const float*)d_in[7];
    const float* d_scale = (const float*)d_in[8];
    const float* elev    = (const float*)d_in[9];
    const float* Rcoef   = (const float*)d_in[10];
    const int*   eidx    = (const int*)d_in[11];

    const int N = in_sizes[3];              // 50000
    const int E = in_sizes[10];             // 128000
    const int B = in_sizes[0] / N;          // 256

    const int* esrc = eidx;
    const int* edst = eidx + E;

    // workspace layout
    char* ws = (char*)d_ws;
    size_t off = 0;
    __half* HTh   = (__half*)(ws + off); off = align256s(off + (size_t)N * B * 2);
    __half* QT    = (__half*)(ws + off); off = align256s(off + (size_t)E * B * 2);
    __half* qaccG = (__half*)(ws + off); off = align256s(off + (size_t)N * B * 2);
    int* incarr   = (int*)(ws + off);    off = align256s(off + (size_t)2 * E * 4);
    int* offsets  = (int*)(ws + off);    off = align256s(off + (size_t)(N + 1) * 4);
    int* cursor   = (int*)(ws + off);    off = align256s(off + (size_t)N * 4);
    const size_t zero_beg = off;
    int* deg      = (int*)(ws + off);    off = align256s(off + (size_t)N * 4);
    int* bsum     = (int*)(ws + off);    off = align256s(off + 256 * 4);
    double* accum = (double*)(ws + off); off += 2 * sizeof(double);
    const size_t zero_len = off - zero_beg;

    hipMemsetAsync(ws + zero_beg, 0, zero_len, stream);

    const int gn = (N + TILE - 1) / TILE;   // 782
    const int gb = B / TILE;                // 4
    const int ge = E / TILE;                // 2000
    const int nb = (N + 255) / 256;         // 196

    k_hist <<<(2 * E + 255) / 256, 256, 0, stream>>>(eidx, deg, 2 * E);
    k_scan1<<<nb, 256, 0, stream>>>(deg, bsum, N);
    k_scan2<<<1, 256, 0, stream>>>(bsum, nb);
    k_scan3<<<nb, 256, 0, stream>>>(deg, bsum, offsets, cursor, N);
    k_fill <<<(E + 255) / 256, 256, 0, stream>>>(esrc, edst, cursor, incarr, E);

    k_build_ht<<<dim3(gn, gb), 256, 0, stream>>>(pred_p, p_scale, p_mean, elev,
                                                 HTh, B, N);
    k_edges<<<dim3(ge, gb), 256, 0, stream>>>(pred_f, f_scale, f_mean, Rcoef,
                                              esrc, edst, HTh, QT,
                                              accum + 1, B, E);
    k_node<<<gn, 256, 0, stream>>>(QT, offsets, incarr, qaccG, N, E);
    k_mass<<<dim3(gn, gb), 256, 0, stream>>>(true_d, d_scale, d_mean,
                                             (const __half2*)qaccG,
                                             accum + 0, B, N);
    k_final<<<1, 1, 0, stream>>>(accum, (float*)d_out,
                                 1.0 / ((double)B * (double)N),
                                 1.0 / ((double)B * (double)E));
}